// Round 1
// 189.411 us; speedup vs baseline: 1.0225x; 1.0225x over previous
//
#include <hip/hip_runtime.h>
#include <hip/hip_bf16.h>

// RelationAwareSelfAttention  N=500, DM=DK=DV=2048, KWIN=10
// Round 7: global_load_lds dwordx4 double-buffered gemm core (m97 lever),
// counted vmcnt (T4), raw s_barrier; BM=64 tile variant for parallelism;
// direct bf16/f32 outputs (no QK/Vt/Y partials, no reduce kernels).
// 6 launches.

#define N_TOK 500
#define MP 512
#define DM 2048
#define KWIN_ 10
#define NREL 21

typedef __hip_bfloat16 bf16;
typedef __attribute__((ext_vector_type(8))) short short8;
typedef __attribute__((ext_vector_type(4))) float floatx4;

#define NS 262144L  // 512*512

__device__ inline float bfj(const short8& v, int j) {
  return __bfloat162float(((const bf16*)&v)[j]);
}

__device__ __forceinline__ void gload16(const bf16* g, bf16* l) {
  __builtin_amdgcn_global_load_lds(
      (const __attribute__((address_space(1))) void*)g,
      (__attribute__((address_space(3))) void*)l, 16, 0, 0);
}

// ---------------- prep: weights transpose+cvt, X/wk cvt ----------------
__global__ __launch_bounds__(256) void prep(
    const float* __restrict__ Wq, const float* __restrict__ Wk,
    const float* __restrict__ Wv, const float* __restrict__ Wo,
    const float* __restrict__ X, const float* __restrict__ wk,
    bf16* __restrict__ WqkT, bf16* __restrict__ WvT, bf16* __restrict__ WoT,
    bf16* __restrict__ Xb, bf16* __restrict__ wkb) {
  int z = blockIdx.z;
  int tid = threadIdx.x;
  if (z == 4) {  // row conversions
    int row = blockIdx.y * 32 + blockIdx.x;
    int c0 = tid * 8;
    bf16 v[8];
    if (row < MP) {
      if (row < N_TOK) {
        const float* p = X + (long)row * DM + c0;
#pragma unroll
        for (int j = 0; j < 8; ++j) v[j] = __float2bfloat16(p[j]);
      } else {
#pragma unroll
        for (int j = 0; j < 8; ++j) v[j] = __float2bfloat16(0.f);
      }
      *(short8*)(Xb + (long)row * DM + c0) = *(short8*)v;
    } else if (row < MP + NREL) {
      int r = row - MP;
      const float* p = wk + (long)r * DM + c0;
#pragma unroll
      for (int j = 0; j < 8; ++j) v[j] = __float2bfloat16(p[j]);
      *(short8*)(wkb + (long)r * DM + c0) = *(short8*)v;
    }
    return;
  }
  const float* W = (z == 0) ? Wq : (z == 1) ? Wk : (z == 2) ? Wv : Wo;
  bf16* Out = (z == 0) ? WqkT
            : (z == 1) ? (WqkT + (long)DM * DM)
            : (z == 2) ? WvT : WoT;
  __shared__ float t[64][68];  // XOR-swizzled granules, conflict-free both sides
  int k0 = blockIdx.y * 64, n0 = blockIdx.x * 64;
  int rr = tid >> 4, cc = (tid & 15) * 4;
  int gsw = cc >> 2;
#pragma unroll
  for (int p = 0; p < 4; ++p) {
    int r = rr + 16 * p;
    float4 v = *(const float4*)(W + (long)(k0 + r) * DM + n0 + cc);
    *(float4*)&t[r][(gsw ^ (r & 3)) * 4] = v;
  }
  __syncthreads();
#pragma unroll
  for (int s0 = 0; s0 < 2; ++s0) {
    int s = tid + s0 * 256;
    int n = s >> 3, c = s & 7;  // 8 lanes per out row -> 128B contiguous
    bf16 v[8];
#pragma unroll
    for (int j = 0; j < 8; ++j) {
      int rowt = c * 8 + j;
      int col = ((n >> 2) ^ (rowt & 3)) * 4 + (n & 3);
      v[j] = __float2bfloat16(t[rowt][col]);
    }
    *(short8*)(Out + (long)(n0 + n) * DM + k0 + c * 8) = *(short8*)v;
  }
}

// ---------------- gemm core: BMx128 tile, 4 waves, gload_lds dbuf ----------
// NT: C[M,N] = A[M,K] @ B[N,K]^T over K-slice [kStart, kStart+kLen).
// BM=128: waves 2x2 of 64x64 (acc 4x4).  BM=64: waves 2x2 of 32x64 (acc 2x4).
// LDS sm[2][256][32]: rows [0,BM) = A tile, rows [128,256) = B tile.
// Staging: global_load_lds dwordx4 (linear dest, wave-uniform base + lane*16).
// Counted vmcnt keeps next-tile DMA in flight across barriers (T4).
// OUT: 0 -> f32 store, 1 -> bf16 store. Store guard: row < mLim.
template <int BM, int OUT>
__device__ __forceinline__ void gemm_core(
    bf16 (*sm)[256][32], const bf16* __restrict__ A, int lda,
    const bf16* __restrict__ B, int ldb, float* __restrict__ Cf,
    bf16* __restrict__ Cb, int ldc, int kStart, int kLen, int row0, int col0,
    int mLim) {
  constexpr int GM = (BM == 128) ? 4 : 2;
  int tid = threadIdx.x;
  int lane = tid & 63, w = tid >> 6;
  int l16 = lane & 15, l4 = lane >> 4;
  int lrow = lane >> 2, lcol = (lane & 3) * 8;  // DMA: lane l -> row l/4, 16B granule l%4
  int wr = (w & 1) * (16 * GM), wc = (w >> 1) * 64;
  const bf16* Ab = A + (long)row0 * lda + kStart;
  const bf16* Bb = B + (long)col0 * ldb + kStart;
  const int arow0 = (BM == 128) ? 32 * w : 16 * w;
  const bf16* aSrc0 = Ab + (long)(arow0 + lrow) * lda + lcol;
  const bf16* aSrc1 = Ab + (long)(arow0 + 16 + lrow) * lda + lcol;
  const bf16* bSrc0 = Bb + (long)(32 * w + lrow) * ldb + lcol;
  const bf16* bSrc1 = Bb + (long)(32 * w + 16 + lrow) * ldb + lcol;

  floatx4 acc[GM][4] = {};

  // per-wave: BM==128 -> 4 DMA ops/tile, BM==64 -> 3
#define STAGE(buf, kk)                                          \
  do {                                                          \
    gload16(aSrc0 + (kk), &sm[buf][arow0][0]);                  \
    if (BM == 128) gload16(aSrc1 + (kk), &sm[buf][arow0 + 16][0]); \
    gload16(bSrc0 + (kk), &sm[buf][128 + 32 * w][0]);           \
    gload16(bSrc1 + (kk), &sm[buf][128 + 32 * w + 16][0]);      \
  } while (0)

  STAGE(0, 0);
  int cur = 0;
  for (int k0 = 0; k0 < kLen; k0 += 32) {
    int kn = k0 + 32;
    if (kn < kLen) {
      STAGE(cur ^ 1, kn);  // next tile in flight across barrier
      if (BM == 128)
        asm volatile("s_waitcnt vmcnt(4)" ::: "memory");  // wait tile k0 only
      else
        asm volatile("s_waitcnt vmcnt(3)" ::: "memory");
    } else {
      asm volatile("s_waitcnt vmcnt(0)" ::: "memory");
    }
    __builtin_amdgcn_s_barrier();        // all waves' tile-k0 DMA landed
    __builtin_amdgcn_sched_barrier(0);   // rule #18: no hoist of ds_reads
    short8 af[GM], bg[4];
#pragma unroll
    for (int g = 0; g < GM; ++g)
      af[g] = *(const short8*)&sm[cur][wr + g * 16 + l16][l4 * 8];
#pragma unroll
    for (int h = 0; h < 4; ++h)
      bg[h] = *(const short8*)&sm[cur][128 + wc + h * 16 + l16][l4 * 8];
#pragma unroll
    for (int g = 0; g < GM; ++g)
#pragma unroll
      for (int h = 0; h < 4; ++h)
        acc[g][h] = __builtin_amdgcn_mfma_f32_16x16x32_bf16(af[g], bg[h],
                                                            acc[g][h], 0, 0, 0);
    __builtin_amdgcn_sched_barrier(0);   // pin reads+mfma before barrier
    asm volatile("s_waitcnt lgkmcnt(0)" ::: "memory");  // reads retired
    __builtin_amdgcn_s_barrier();        // safe to overwrite buf[cur] next iter
    cur ^= 1;
  }
#undef STAGE

  // C/D layout: col = lane&15, row = (lane>>4)*4 + i  [m89-verified]
#pragma unroll
  for (int g = 0; g < GM; ++g)
#pragma unroll
    for (int h = 0; h < 4; ++h)
#pragma unroll
      for (int i = 0; i < 4; ++i) {
        long r = row0 + wr + g * 16 + l4 * 4 + i;
        long c = col0 + wc + h * 16 + l16;
        if (r < mLim) {
          if (OUT == 0)
            Cf[r * ldc + c] = acc[g][h][i];
          else
            Cb[r * ldc + c] = __float2bfloat16(acc[g][h][i]);
        }
      }
}

// Merged QK (128 blocks, 128x128) + Vt (128 blocks, 64x128) = 256 blocks,
// K=2048 unsplit, direct bf16 output (no partials, no reduce).
__global__ __launch_bounds__(256, 2) void gemm_qkvt(
    const bf16* __restrict__ Xb, const bf16* __restrict__ WqkT,
    const bf16* __restrict__ WvT, bf16* __restrict__ QKbf,
    bf16* __restrict__ Vtb) {
  __shared__ __align__(16) bf16 sm[2][256][32];
  int id = blockIdx.x;
  if (id < 128) {  // QK: C[512,4096] = Xb @ WqkT^T
    int row0 = (id >> 5) * 128, col0 = (id & 31) * 128;
    gemm_core<128, 1>(sm, Xb, DM, WqkT, DM, nullptr, QKbf, 4096, 0, DM, row0,
                      col0, MP);
  } else {  // Vt: C[2048,512] = WvT @ Xb^T
    int t = id - 128;
    int row0 = (t >> 2) * 64, col0 = (t & 3) * 128;
    gemm_core<64, 1>(sm, WvT, DM, Xb, DM, nullptr, Vtb, MP, 0, DM, row0, col0,
                     DM);
  }
}

// Generic split-K gemm. grid (N/128, M/BM, splits).
template <int BM, int OUT>
__global__ __launch_bounds__(256, 2) void gemm_k(
    const bf16* __restrict__ A, int lda, const bf16* __restrict__ B, int ldb,
    float* __restrict__ Cf, bf16* __restrict__ Cb, int ldc, int sliceK,
    long cstride, int mLim) {
  __shared__ __align__(16) bf16 sm[2][256][32];
  float* cf = (OUT == 0) ? Cf + (long)blockIdx.z * cstride : nullptr;
  gemm_core<BM, OUT>(sm, A, lda, B, ldb, cf, Cb, ldc, blockIdx.z * sliceK,
                     sliceK, blockIdx.y * BM, blockIdx.x * 128, mLim);
}

// QR (21 dots of K=2048) + sum 4 S-partials + scale + bias + mask + softmax.
__global__ __launch_bounds__(256) void softmax_qr(
    const float* __restrict__ Sp, const bf16* __restrict__ QKbf,
    const bf16* __restrict__ wkb, const int* __restrict__ mask,
    float* __restrict__ Aout, bf16* __restrict__ Abf) {
  int i = blockIdx.x;
  int tid = threadIdx.x;
  if (i >= N_TOK) {  // pad rows of Abf -> 0
    Abf[(long)i * MP + tid] = __float2bfloat16(0.f);
    Abf[(long)i * MP + tid + 256] = __float2bfloat16(0.f);
    return;
  }
  int lane = tid & 63, w = tid >> 6;
  __shared__ float sQR[24];
  __shared__ float red[4];
  // ---- QR: wave w handles r = w, w+4, ... (Q row preloaded once) ----
  short8 q[4];
#pragma unroll
  for (int s = 0; s < 4; ++s)
    q[s] = *(const short8*)(QKbf + (long)i * 4096 + s * 512 + lane * 8);
  for (int r = w; r < NREL; r += 4) {
    float p = 0.f;
#pragma unroll
    for (int s = 0; s < 4; ++s) {
      short8 wv = *(const short8*)(wkb + (long)r * DM + s * 512 + lane * 8);
#pragma unroll
      for (int j = 0; j < 8; ++j) p += bfj(q[s], j) * bfj(wv, j);
    }
#pragma unroll
    for (int o = 32; o > 0; o >>= 1) p += __shfl_down(p, o);
    if (lane == 0) sQR[r] = p;
  }
  __syncthreads();
  // ---- softmax over j (each thread owns j0=tid, j1=tid+256) ----
  const float scale = 0.022097086912079608f;  // 1/sqrt(2048)
  float v0, v1 = -1e30f;
  int j0 = tid, j1 = tid + 256;
  {
    float s = Sp[(long)i * MP + j0] + Sp[NS + (long)i * MP + j0] +
              Sp[2 * NS + (long)i * MP + j0] + Sp[3 * NS + (long)i * MP + j0];
    int rel = j0 - i;
    rel = rel < -KWIN_ ? -KWIN_ : (rel > KWIN_ ? KWIN_ : rel);
    s = scale * (s + sQR[rel + KWIN_]);
    if (mask[(long)i * N_TOK + j0] == 0) s = -1e9f;
    v0 = s;
  }
  if (j1 < N_TOK) {
    float s = Sp[(long)i * MP + j1] + Sp[NS + (long)i * MP + j1] +
              Sp[2 * NS + (long)i * MP + j1] + Sp[3 * NS + (long)i * MP + j1];
    int rel = j1 - i;
    rel = rel < -KWIN_ ? -KWIN_ : (rel > KWIN_ ? KWIN_ : rel);
    s = scale * (s + sQR[rel + KWIN_]);
    if (mask[(long)i * N_TOK + j1] == 0) s = -1e9f;
    v1 = s;
  }
  float mx = fmaxf(v0, v1);
#pragma unroll
  for (int o = 32; o > 0; o >>= 1) mx = fmaxf(mx, __shfl_down(mx, o));
  if (lane == 0) red[w] = mx;
  __syncthreads();
  if (tid == 0) red[0] = fmaxf(fmaxf(red[0], red[1]), fmaxf(red[2], red[3]));
  __syncthreads();
  mx = red[0];
  __syncthreads();
  float e0 = expf(v0 - mx);
  float e1 = (j1 < N_TOK) ? expf(v1 - mx) : 0.f;
  float sum = e0 + e1;
#pragma unroll
  for (int o = 32; o > 0; o >>= 1) sum += __shfl_down(sum, o);
  if (lane == 0) red[w] = sum;
  __syncthreads();
  if (tid == 0) red[0] = red[0] + red[1] + red[2] + red[3];
  __syncthreads();
  float inv = 1.f / red[0];
  float a0 = e0 * inv, a1 = e1 * inv;
  Aout[(long)i * N_TOK + j0] = a0;
  if (j1 < N_TOK) Aout[(long)i * N_TOK + j1] = a1;
  Abf[(long)i * MP + j0] = __float2bfloat16(a0);
  Abf[(long)i * MP + j1] = __float2bfloat16(a1);  // j1>=500 -> 0
}

extern "C" void kernel_launch(void* const* d_in, const int* in_sizes, int n_in,
                              void* d_out, int out_size, void* d_ws,
                              size_t ws_size, hipStream_t stream) {
  const float* X = (const float*)d_in[0];
  const int* mask = (const int*)d_in[1];
  const float* Wq = (const float*)d_in[2];
  const float* Wk = (const float*)d_in[3];
  const float* Wv = (const float*)d_in[4];
  const float* Wo = (const float*)d_in[5];
  const float* wk = (const float*)d_in[6];

  float* Yout = (float*)d_out;            // [500,2048]
  float* Aout = Yout + (long)N_TOK * DM;  // [500,500]

  const long MB = 1 << 20;
  char* p = (char*)d_ws;
  bf16* Xb = (bf16*)p;                    // [512][2048]        2 MB
  bf16* WqkT = (bf16*)(p + 2 * MB);       // [4096][2048]      16 MB
  bf16* WvT = (bf16*)(p + 18 * MB);       // [2048][2048]       8 MB
  bf16* WoT = (bf16*)(p + 26 * MB);       // [2048][2048]       8 MB
  bf16* wkb = (bf16*)(p + 34 * MB);       // [21][2048]
  bf16* QKbf = (bf16*)(p + 35 * MB);      // [512][4096]        4 MB
  bf16* Vtb = (bf16*)(p + 39 * MB);       // [2048][512]        2 MB
  float* Sp = (float*)(p + 41 * MB);      // [4][512][512]      4 MB
  bf16* Abf = (bf16*)(p + 45 * MB);       // [512][512]       0.5 MB
  bf16* AVbf = (bf16*)(p + 46 * MB);      // [512][2048]        2 MB

  dim3 b256(256);

  // 1. prep: weights -> transposed bf16; X/wk -> bf16
  prep<<<dim3(32, 32, 5), b256, 0, stream>>>(Wq, Wk, Wv, Wo, X, wk, WqkT, WvT,
                                             WoT, Xb, wkb);
  // 2. QK (128x128, 128 blk) + Vt (64x128, 128 blk), K=2048, direct bf16
  gemm_qkvt<<<dim3(256), b256, 0, stream>>>(Xb, WqkT, WvT, QKbf, Vtb);
  // 3. S partials: Q @ K^T, 64x128 tiles, splitK4 (unscaled) -> 128 blocks
  gemm_k<64, 0><<<dim3(4, 8, 4), b256, 0, stream>>>(
      QKbf, 4096, QKbf + 2048, 4096, Sp, nullptr, MP, 512, NS, MP);
  // 4. QR + softmax -> Aout (d_out) + Abf
  softmax_qr<<<dim3(MP), b256, 0, stream>>>(Sp, QKbf, wkb, mask, Aout, Abf);
  // 5. AV = Abf @ Vtb^T -> bf16, 64x128 tiles, 128 blocks
  gemm_k<64, 1><<<dim3(16, 8, 1), b256, 0, stream>>>(
      Abf, MP, Vtb, MP, nullptr, AVbf, DM, MP, 0, MP);
  // 6. Y = AVbf @ WoT^T -> f32 d_out directly (rows < 500), 128 blocks
  gemm_k<64, 0><<<dim3(16, 8, 1), b256, 0, stream>>>(
      AVbf, DM, WoT, DM, Yout, nullptr, DM, DM, 0, N_TOK);
}

// Round 2
// 178.758 us; speedup vs baseline: 1.0835x; 1.0596x over previous
//
#include <hip/hip_runtime.h>
#include <hip/hip_bf16.h>

// RelationAwareSelfAttention  N=500, DM=DK=DV=2048, KWIN=10
// Round 8: 4-deep gload_lds pipeline (counted vmcnt 12/9, tile staged 3 iters
// ahead to cover ~900cyc HBM latency at 1 wave/SIMD), LDS read-swizzle via
// pre-swizzled global source (8-way -> 2-way bank conflict), S splitK8.
// 6 launches.

#define N_TOK 500
#define MP 512
#define DM 2048
#define KWIN_ 10
#define NREL 21

typedef __hip_bfloat16 bf16;
typedef __attribute__((ext_vector_type(8))) short short8;
typedef __attribute__((ext_vector_type(4))) float floatx4;

#define NS 262144L  // 512*512

__device__ inline float bfj(const short8& v, int j) {
  return __bfloat162float(((const bf16*)&v)[j]);
}

__device__ __forceinline__ void gload16(const bf16* g, bf16* l) {
  __builtin_amdgcn_global_load_lds(
      (const __attribute__((address_space(1))) void*)g,
      (__attribute__((address_space(3))) void*)l, 16, 0, 0);
}

// ---------------- prep: weights transpose+cvt, X/wk cvt ----------------
__global__ __launch_bounds__(256) void prep(
    const float* __restrict__ Wq, const float* __restrict__ Wk,
    const float* __restrict__ Wv, const float* __restrict__ Wo,
    const float* __restrict__ X, const float* __restrict__ wk,
    bf16* __restrict__ WqkT, bf16* __restrict__ WvT, bf16* __restrict__ WoT,
    bf16* __restrict__ Xb, bf16* __restrict__ wkb) {
  int z = blockIdx.z;
  int tid = threadIdx.x;
  if (z == 4) {  // row conversions
    int row = blockIdx.y * 32 + blockIdx.x;
    int c0 = tid * 8;
    bf16 v[8];
    if (row < MP) {
      if (row < N_TOK) {
        const float* p = X + (long)row * DM + c0;
#pragma unroll
        for (int j = 0; j < 8; ++j) v[j] = __float2bfloat16(p[j]);
      } else {
#pragma unroll
        for (int j = 0; j < 8; ++j) v[j] = __float2bfloat16(0.f);
      }
      *(short8*)(Xb + (long)row * DM + c0) = *(short8*)v;
    } else if (row < MP + NREL) {
      int r = row - MP;
      const float* p = wk + (long)r * DM + c0;
#pragma unroll
      for (int j = 0; j < 8; ++j) v[j] = __float2bfloat16(p[j]);
      *(short8*)(wkb + (long)r * DM + c0) = *(short8*)v;
    }
    return;
  }
  const float* W = (z == 0) ? Wq : (z == 1) ? Wk : (z == 2) ? Wv : Wo;
  bf16* Out = (z == 0) ? WqkT
            : (z == 1) ? (WqkT + (long)DM * DM)
            : (z == 2) ? WvT : WoT;
  __shared__ float t[64][68];  // XOR-swizzled granules, conflict-free both sides
  int k0 = blockIdx.y * 64, n0 = blockIdx.x * 64;
  int rr = tid >> 4, cc = (tid & 15) * 4;
  int gsw = cc >> 2;
#pragma unroll
  for (int p = 0; p < 4; ++p) {
    int r = rr + 16 * p;
    float4 v = *(const float4*)(W + (long)(k0 + r) * DM + n0 + cc);
    *(float4*)&t[r][(gsw ^ (r & 3)) * 4] = v;
  }
  __syncthreads();
#pragma unroll
  for (int s0 = 0; s0 < 2; ++s0) {
    int s = tid + s0 * 256;
    int n = s >> 3, c = s & 7;  // 8 lanes per out row -> 128B contiguous
    bf16 v[8];
#pragma unroll
    for (int j = 0; j < 8; ++j) {
      int rowt = c * 8 + j;
      int col = ((n >> 2) ^ (rowt & 3)) * 4 + (n & 3);
      v[j] = __float2bfloat16(t[rowt][col]);
    }
    *(short8*)(Out + (long)(n0 + n) * DM + k0 + c * 8) = *(short8*)v;
  }
}

// ---------------- gemm core: BMx128 tile, 4 waves, 4-deep gload_lds --------
// NT: C[M,N] = A[M,K] @ B[N,K]^T over K-slice [kStart, kStart+kLen).
// BM=128: waves 2x2 of 64x64 (acc 4x4).  BM=64: waves 2x2 of 32x64 (acc 2x4).
// LDS: D=4 buffers of (BM+128) rows x 32 bf16. A rows [0,BM), B [BM,BM+128).
// Staging: global_load_lds dwordx4, linear dest (lane l -> row l/4, gran l%4).
// Tile t staged at iter t-3 (3-iter latency slack); counted vmcnt = (D-1)*LPT.
// Swizzle: data granule g of row R stored at physical g ^ ((R>>1)&3); realized
// by permuting the per-lane GLOBAL source granule (T21: linear dest + inv-swz
// source + swz read). Read granule = l4 ^ ((l16>>1)&3) -> 2-way conflicts.
// OUT: 0 -> f32 store, 1 -> bf16 store. Store guard: row < mLim. NT >= 4.
template <int BM, int OUT>
__device__ __forceinline__ void gemm_core(
    bf16* sm, const bf16* __restrict__ A, int lda, const bf16* __restrict__ B,
    int ldb, float* __restrict__ Cf, bf16* __restrict__ Cb, int ldc,
    int kStart, int kLen, int row0, int col0, int mLim) {
  constexpr int GM = (BM == 128) ? 4 : 2;
  constexpr int ROWS = BM + 128;
  constexpr int BUFE = ROWS * 32;  // elements per buffer
  int tid = threadIdx.x;
  int lane = tid & 63, w = tid >> 6;
  int l16 = lane & 15, l4 = lane >> 4;
  int lrow = lane >> 2;                              // dest row within 16-row blk
  int lcol = ((lane & 3) ^ ((lane >> 3) & 3)) * 8;   // inv-swizzled src granule
  int wr = (w & 1) * (16 * GM), wc = (w >> 1) * 64;
  const bf16* Ab = A + (long)row0 * lda + kStart;
  const bf16* Bb = B + (long)col0 * ldb + kStart;
  const int arow0 = (BM == 128) ? 32 * w : 16 * w;
  const int brow0 = BM + 32 * w;
  const bf16* aSrc0 = Ab + (long)(arow0 + lrow) * lda + lcol;
  const bf16* aSrc1 = Ab + (long)(arow0 + 16 + lrow) * lda + lcol;
  const bf16* bSrc0 = Bb + (long)(32 * w + lrow) * ldb + lcol;
  const bf16* bSrc1 = Bb + (long)(32 * w + 16 + lrow) * ldb + lcol;

  floatx4 acc[GM][4] = {};
  int NT = kLen >> 5;

  // per-wave DMA ops per tile: BM==128 -> 4, BM==64 -> 3
#define STAGE(buf, kk)                                                \
  do {                                                                \
    bf16* bp = sm + (buf) * BUFE;                                     \
    gload16(aSrc0 + (kk), bp + arow0 * 32);                           \
    if (BM == 128) gload16(aSrc1 + (kk), bp + (arow0 + 16) * 32);     \
    gload16(bSrc0 + (kk), bp + brow0 * 32);                           \
    gload16(bSrc1 + (kk), bp + (brow0 + 16) * 32);                    \
  } while (0)

  STAGE(0, 0);        // prologue: tiles 0..2 in flight (NT >= 4 always)
  STAGE(1, 32);
  STAGE(2, 64);
  int rd = ((l16 >> 1) & 3) * 8;  // read-side swizzle key (elems)
  for (int t = 0; t < NT; ++t) {
    if (t + 3 < NT) {
      STAGE((t + 3) & 3, (t + 3) * 32);
      // outstanding = tiles t..t+3; wait leaves newest 3 -> tile t landed
      if (BM == 128)
        asm volatile("s_waitcnt vmcnt(12)" ::: "memory");
      else
        asm volatile("s_waitcnt vmcnt(9)" ::: "memory");
    } else {
      asm volatile("s_waitcnt vmcnt(0)" ::: "memory");  // tail drain
    }
    __builtin_amdgcn_s_barrier();       // all waves' tile-t DMA landed
    __builtin_amdgcn_sched_barrier(0);  // rule #18: no hoist above barrier
    const bf16* bp = sm + (t & 3) * BUFE;
    short8 af[GM], bg[4];
#pragma unroll
    for (int g = 0; g < GM; ++g)
      af[g] = *(const short8*)(bp + (wr + g * 16 + l16) * 32 + (l4 * 8 ^ rd));
#pragma unroll
    for (int h = 0; h < 4; ++h)
      bg[h] = *(const short8*)(bp + (BM + wc + h * 16 + l16) * 32 + (l4 * 8 ^ rd));
#pragma unroll
    for (int g = 0; g < GM; ++g)
#pragma unroll
      for (int h = 0; h < 4; ++h)
        acc[g][h] = __builtin_amdgcn_mfma_f32_16x16x32_bf16(af[g], bg[h],
                                                            acc[g][h], 0, 0, 0);
    __builtin_amdgcn_sched_barrier(0);  // pin reads+mfma before barrier
    asm volatile("s_waitcnt lgkmcnt(0)" ::: "memory");  // reads retired
    __builtin_amdgcn_s_barrier();  // buf (t+1)&3 (read iter t-... ) reusable
  }
#undef STAGE

  // C/D layout: col = lane&15, row = (lane>>4)*4 + i  [m89-verified]
#pragma unroll
  for (int g = 0; g < GM; ++g)
#pragma unroll
    for (int h = 0; h < 4; ++h)
#pragma unroll
      for (int i = 0; i < 4; ++i) {
        long r = row0 + wr + g * 16 + l4 * 4 + i;
        long c = col0 + wc + h * 16 + l16;
        if (r < mLim) {
          if (OUT == 0)
            Cf[r * ldc + c] = acc[g][h][i];
          else
            Cb[r * ldc + c] = __float2bfloat16(acc[g][h][i]);
        }
      }
}

// Merged QK (128 blocks, 128x128) + Vt (128 blocks, 64x128) = 256 blocks,
// K=2048 unsplit, direct bf16 output.
__global__ __launch_bounds__(256, 2) void gemm_qkvt(
    const bf16* __restrict__ Xb, const bf16* __restrict__ WqkT,
    const bf16* __restrict__ WvT, bf16* __restrict__ QKbf,
    bf16* __restrict__ Vtb) {
  __shared__ __align__(16) bf16 sm[4 * 256 * 32];  // 64 KB (max of both cores)
  int id = blockIdx.x;
  if (id < 128) {  // QK: C[512,4096] = Xb @ WqkT^T
    int row0 = (id >> 5) * 128, col0 = (id & 31) * 128;
    gemm_core<128, 1>(sm, Xb, DM, WqkT, DM, nullptr, QKbf, 4096, 0, DM, row0,
                      col0, MP);
  } else {  // Vt: C[2048,512] = WvT @ Xb^T
    int t = id - 128;
    int row0 = (t >> 2) * 64, col0 = (t & 3) * 128;
    gemm_core<64, 1>(sm, WvT, DM, Xb, DM, nullptr, Vtb, MP, 0, DM, row0, col0,
                     DM);
  }
}

// Generic split-K gemm. grid (N/128, M/BM, splits).
template <int BM, int OUT>
__global__ __launch_bounds__(256, 2) void gemm_k(
    const bf16* __restrict__ A, int lda, const bf16* __restrict__ B, int ldb,
    float* __restrict__ Cf, bf16* __restrict__ Cb, int ldc, int sliceK,
    long cstride, int mLim) {
  __shared__ __align__(16) bf16 sm[4 * (BM + 128) * 32];
  float* cf = (OUT == 0) ? Cf + (long)blockIdx.z * cstride : nullptr;
  gemm_core<BM, OUT>(sm, A, lda, B, ldb, cf, Cb, ldc, blockIdx.z * sliceK,
                     sliceK, blockIdx.y * BM, blockIdx.x * 128, mLim);
}

// QR (21 dots of K=2048) + sum 8 S-partials + scale + bias + mask + softmax.
__global__ __launch_bounds__(256) void softmax_qr(
    const float* __restrict__ Sp, const bf16* __restrict__ QKbf,
    const bf16* __restrict__ wkb, const int* __restrict__ mask,
    float* __restrict__ Aout, bf16* __restrict__ Abf) {
  int i = blockIdx.x;
  int tid = threadIdx.x;
  if (i >= N_TOK) {  // pad rows of Abf -> 0
    Abf[(long)i * MP + tid] = __float2bfloat16(0.f);
    Abf[(long)i * MP + tid + 256] = __float2bfloat16(0.f);
    return;
  }
  int lane = tid & 63, w = tid >> 6;
  __shared__ float sQR[24];
  __shared__ float red[4];
  // ---- QR: wave w handles r = w, w+4, ... (Q row preloaded once) ----
  short8 q[4];
#pragma unroll
  for (int s = 0; s < 4; ++s)
    q[s] = *(const short8*)(QKbf + (long)i * 4096 + s * 512 + lane * 8);
  for (int r = w; r < NREL; r += 4) {
    float p = 0.f;
#pragma unroll
    for (int s = 0; s < 4; ++s) {
      short8 wv = *(const short8*)(wkb + (long)r * DM + s * 512 + lane * 8);
#pragma unroll
      for (int j = 0; j < 8; ++j) p += bfj(q[s], j) * bfj(wv, j);
    }
#pragma unroll
    for (int o = 32; o > 0; o >>= 1) p += __shfl_down(p, o);
    if (lane == 0) sQR[r] = p;
  }
  __syncthreads();
  // ---- softmax over j (each thread owns j0=tid, j1=tid+256) ----
  const float scale = 0.022097086912079608f;  // 1/sqrt(2048)
  float v0, v1 = -1e30f;
  int j0 = tid, j1 = tid + 256;
  {
    float s = 0.f;
#pragma unroll
    for (int z = 0; z < 8; ++z) s += Sp[z * NS + (long)i * MP + j0];
    int rel = j0 - i;
    rel = rel < -KWIN_ ? -KWIN_ : (rel > KWIN_ ? KWIN_ : rel);
    s = scale * (s + sQR[rel + KWIN_]);
    if (mask[(long)i * N_TOK + j0] == 0) s = -1e9f;
    v0 = s;
  }
  if (j1 < N_TOK) {
    float s = 0.f;
#pragma unroll
    for (int z = 0; z < 8; ++z) s += Sp[z * NS + (long)i * MP + j1];
    int rel = j1 - i;
    rel = rel < -KWIN_ ? -KWIN_ : (rel > KWIN_ ? KWIN_ : rel);
    s = scale * (s + sQR[rel + KWIN_]);
    if (mask[(long)i * N_TOK + j1] == 0) s = -1e9f;
    v1 = s;
  }
  float mx = fmaxf(v0, v1);
#pragma unroll
  for (int o = 32; o > 0; o >>= 1) mx = fmaxf(mx, __shfl_down(mx, o));
  if (lane == 0) red[w] = mx;
  __syncthreads();
  if (tid == 0) red[0] = fmaxf(fmaxf(red[0], red[1]), fmaxf(red[2], red[3]));
  __syncthreads();
  mx = red[0];
  __syncthreads();
  float e0 = expf(v0 - mx);
  float e1 = (j1 < N_TOK) ? expf(v1 - mx) : 0.f;
  float sum = e0 + e1;
#pragma unroll
  for (int o = 32; o > 0; o >>= 1) sum += __shfl_down(sum, o);
  if (lane == 0) red[w] = sum;
  __syncthreads();
  if (tid == 0) red[0] = red[0] + red[1] + red[2] + red[3];
  __syncthreads();
  float inv = 1.f / red[0];
  float a0 = e0 * inv, a1 = e1 * inv;
  Aout[(long)i * N_TOK + j0] = a0;
  if (j1 < N_TOK) Aout[(long)i * N_TOK + j1] = a1;
  Abf[(long)i * MP + j0] = __float2bfloat16(a0);
  Abf[(long)i * MP + j1] = __float2bfloat16(a1);  // j1>=500 -> 0
}

extern "C" void kernel_launch(void* const* d_in, const int* in_sizes, int n_in,
                              void* d_out, int out_size, void* d_ws,
                              size_t ws_size, hipStream_t stream) {
  const float* X = (const float*)d_in[0];
  const int* mask = (const int*)d_in[1];
  const float* Wq = (const float*)d_in[2];
  const float* Wk = (const float*)d_in[3];
  const float* Wv = (const float*)d_in[4];
  const float* Wo = (const float*)d_in[5];
  const float* wk = (const float*)d_in[6];

  float* Yout = (float*)d_out;            // [500,2048]
  float* Aout = Yout + (long)N_TOK * DM;  // [500,500]

  const long MB = 1 << 20;
  char* p = (char*)d_ws;
  bf16* Xb = (bf16*)p;                    // [512][2048]        2 MB
  bf16* WqkT = (bf16*)(p + 2 * MB);       // [4096][2048]      16 MB
  bf16* WvT = (bf16*)(p + 18 * MB);       // [2048][2048]       8 MB
  bf16* WoT = (bf16*)(p + 26 * MB);       // [2048][2048]       8 MB
  bf16* wkb = (bf16*)(p + 34 * MB);       // [21][2048]
  bf16* QKbf = (bf16*)(p + 35 * MB);      // [512][4096]        4 MB
  bf16* Vtb = (bf16*)(p + 39 * MB);       // [2048][512]        2 MB
  float* Sp = (float*)(p + 41 * MB);      // [8][512][512]      8 MB
  bf16* Abf = (bf16*)(p + 49 * MB);       // [512][512]       0.5 MB
  bf16* AVbf = (bf16*)(p + 50 * MB);      // [512][2048]        2 MB

  dim3 b256(256);

  // 1. prep: weights -> transposed bf16; X/wk -> bf16
  prep<<<dim3(32, 32, 5), b256, 0, stream>>>(Wq, Wk, Wv, Wo, X, wk, WqkT, WvT,
                                             WoT, Xb, wkb);
  // 2. QK (128x128, 128 blk) + Vt (64x128, 128 blk), K=2048, direct bf16
  gemm_qkvt<<<dim3(256), b256, 0, stream>>>(Xb, WqkT, WvT, QKbf, Vtb);
  // 3. S partials: Q @ K^T, 64x128 tiles, splitK8 (unscaled) -> 256 blocks
  gemm_k<64, 0><<<dim3(4, 8, 8), b256, 0, stream>>>(
      QKbf, 4096, QKbf + 2048, 4096, Sp, nullptr, MP, 256, NS, MP);
  // 4. QR + softmax -> Aout (d_out) + Abf
  softmax_qr<<<dim3(MP), b256, 0, stream>>>(Sp, QKbf, wkb, mask, Aout, Abf);
  // 5. AV = Abf @ Vtb^T -> bf16, 64x128 tiles, 128 blocks
  gemm_k<64, 1><<<dim3(16, 8, 1), b256, 0, stream>>>(
      Abf, MP, Vtb, MP, nullptr, AVbf, DM, MP, 0, MP);
  // 6. Y = AVbf @ WoT^T -> f32 d_out directly (rows < 500), 128 blocks
  gemm_k<64, 0><<<dim3(16, 8, 1), b256, 0, stream>>>(
      AVbf, DM, WoT, DM, Yout, nullptr, DM, DM, 0, N_TOK);
}